// Round 9
// baseline (66.367 us; speedup 1.0000x reference)
//
#include <hip/hip_runtime.h>
#include <hip/hip_bf16.h>

#define N_ASSETS 4096
#define DMODEL 512
#define DKQ 128
#define NUM_EMB 1024

// Fold 1/sqrt(dk) * log2(e) into stored Q so the score epilogue is exp2(g*acc).
#define SCLQ 0.12752789f

typedef float f32x4 __attribute__((ext_vector_type(4)));
typedef short s16x8 __attribute__((ext_vector_type(8)));

__device__ __forceinline__ unsigned short f2bf(float x) {
    unsigned u = __float_as_uint(x);
    u += 0x7FFF + ((u >> 16) & 1);
    return (unsigned short)(u >> 16);
}

__device__ __forceinline__ unsigned pk2(float lo, float hi) {
    __hip_bfloat162 h = __float22bfloat162_rn(make_float2(lo, hi));
    return *(unsigned*)&h;
}

__device__ __forceinline__ s16x8 ld8(const unsigned short* p) {
    return *(const s16x8*)p;
}

// ---------------- K_prep: small setup only (21 blocks) ----------------
// blocks 0..3  : gate[e] = sigmoid(rank_emb[e] @ wL + bL)   (1024)
// blocks 4..19 : weff4 partials: block r=(s,q): dout slice s (128 rows) x
//                din quarter q (128 cols); coalesced row-major reads.
// block  20    : weff4[2048] = bv . wf
__global__ __launch_bounds__(256) void k_prep(const float* __restrict__ remb,
                                              const float* __restrict__ wLw,
                                              const float* __restrict__ wLb,
                                              const float* __restrict__ Wv,
                                              const float* __restrict__ bv,
                                              const float* __restrict__ wfw,
                                              float* __restrict__ gate,
                                              float* __restrict__ weff4) {
    int bid = blockIdx.x;
    int tid = threadIdx.x;
    if (bid < 4) {
        int e = bid * 256 + tid;
        float s = wLb[0];
#pragma unroll
        for (int j = 0; j < 32; ++j) s += remb[e * 32 + j] * wLw[j];
        gate[e] = 1.f / (1.f + __expf(-s));
    } else if (bid < 20) {
        int r = bid - 4;     // 0..15
        int s = r >> 2;      // dout slice (128 rows)
        int q = r & 3;       // din quarter (128 cols)
        if (tid < 128) {
            int din = q * 128 + tid;
            int dbase = s * 128;
            const float* wp = Wv + (size_t)dbase * 512 + din;
            float a = 0.f;
#pragma unroll 8
            for (int j = 0; j < 128; ++j)
                a += wp[(size_t)j * 512] * wfw[dbase + j];
            weff4[s * 512 + din] = a;
        }
    } else {
        if (tid < 64) {
            float s = 0.f;
#pragma unroll
            for (int j = 0; j < 8; ++j) s += bv[tid * 8 + j] * wfw[tid * 8 + j];
#pragma unroll
            for (int m = 1; m < 64; m <<= 1) s += __shfl_xor(s, m);
            if (tid == 0) weff4[2048] = s;
        }
    }
}

// ---------------- K_proj: fused X->regs + u GEMV + Q/K projection ----------------
// Grid (256, 2): block owns 16 rows x 128 cols of [Q|K]. 4 waves, each 32 cols,
// 32 MFMA. W fragments converted fp32->bf16 in-register (no staging buffer;
// Wq/Wk are L2-resident). Wave 0 of y==0 also computes u = X.weff + c.
__global__ __launch_bounds__(256) void k_proj(const float* __restrict__ X,
                                              const float* __restrict__ weff4,
                                              const float* __restrict__ Wq,
                                              const float* __restrict__ Wk,
                                              const float* __restrict__ bq,
                                              const float* __restrict__ bk,
                                              unsigned short* __restrict__ qb,
                                              unsigned short* __restrict__ kb,
                                              float* __restrict__ u) {
    int tid = threadIdx.x;
    int lane = tid & 63, w = tid >> 6;
    int l15 = lane & 15, lhi = lane >> 4;
    int m0 = blockIdx.x * 16;
    int n0w = blockIdx.y * 128 + w * 32;

    const float* xrow = X + (size_t)(m0 + l15) * DMODEL + lhi * 8;

    s16x8 af[16];
    float us = 0.f;
    bool dou = (w == 0) && (blockIdx.y == 0);
#pragma unroll
    for (int kc = 0; kc < 16; ++kc) {
        float4 a = *(const float4*)(xrow + kc * 32);
        float4 b = *(const float4*)(xrow + kc * 32 + 4);
        if (dou) {
            int off = kc * 32 + lhi * 8;
            float4 p0 = *(const float4*)(weff4 + off);
            float4 p1 = *(const float4*)(weff4 + 512 + off);
            float4 p2 = *(const float4*)(weff4 + 1024 + off);
            float4 p3 = *(const float4*)(weff4 + 1536 + off);
            float4 q0 = *(const float4*)(weff4 + off + 4);
            float4 q1 = *(const float4*)(weff4 + 512 + off + 4);
            float4 q2 = *(const float4*)(weff4 + 1024 + off + 4);
            float4 q3 = *(const float4*)(weff4 + 1536 + off + 4);
            float wax = p0.x + p1.x + p2.x + p3.x;
            float way = p0.y + p1.y + p2.y + p3.y;
            float waz = p0.z + p1.z + p2.z + p3.z;
            float waw = p0.w + p1.w + p2.w + p3.w;
            float wbx = q0.x + q1.x + q2.x + q3.x;
            float wby = q0.y + q1.y + q2.y + q3.y;
            float wbz = q0.z + q1.z + q2.z + q3.z;
            float wbw = q0.w + q1.w + q2.w + q3.w;
            us += a.x * wax + a.y * way + a.z * waz + a.w * waw
                + b.x * wbx + b.y * wby + b.z * wbz + b.w * wbw;
        }
        union { s16x8 v; unsigned q[4]; } fr;
        fr.q[0] = pk2(a.x, a.y);
        fr.q[1] = pk2(a.z, a.w);
        fr.q[2] = pk2(b.x, b.y);
        fr.q[3] = pk2(b.z, b.w);
        af[kc] = fr.v;
    }
    if (dou) {
        us += __shfl_xor(us, 16);
        us += __shfl_xor(us, 32);
        if (lane < 16) u[m0 + lane] = us + weff4[2048];
    }

    f32x4 zero4 = {0.f, 0.f, 0.f, 0.f};
    f32x4 acc[2];
#pragma unroll
    for (int ni = 0; ni < 2; ++ni) acc[ni] = zero4;

    // W row base for each ni-fragment (wave-uniform Wq/Wk selection: the
    // 128-boundary is 16-row aligned, so each fragment is fully one side).
    const float* wrow[2];
    float biasv[2];
#pragma unroll
    for (int ni = 0; ni < 2; ++ni) {
        int n = n0w + ni * 16 + l15;
        if (n < 128) { wrow[ni] = Wq + (size_t)n * 512; biasv[ni] = bq[n]; }
        else         { wrow[ni] = Wk + (size_t)(n - 128) * 512; biasv[ni] = bk[n - 128]; }
    }

#pragma unroll
    for (int k0 = 0; k0 < 16; ++k0) {
#pragma unroll
        for (int ni = 0; ni < 2; ++ni) {
            const float* wp = wrow[ni] + k0 * 32 + lhi * 8;
            float4 wa = *(const float4*)wp;
            float4 wb = *(const float4*)(wp + 4);
            union { s16x8 v; unsigned q[4]; } fr;
            fr.q[0] = pk2(wa.x, wa.y);
            fr.q[1] = pk2(wa.z, wa.w);
            fr.q[2] = pk2(wb.x, wb.y);
            fr.q[3] = pk2(wb.z, wb.w);
            acc[ni] = __builtin_amdgcn_mfma_f32_16x16x32_bf16(af[k0], fr.v, acc[ni], 0, 0, 0);
        }
    }

#pragma unroll
    for (int ni = 0; ni < 2; ++ni) {
        int n = n0w + ni * 16 + l15;
#pragma unroll
        for (int r = 0; r < 4; ++r) {
            int m = m0 + lhi * 4 + r;
            float v = acc[ni][r] + biasv[ni];
            if (n < 128) qb[m * 128 + n] = f2bf(v * SCLQ);
            else         kb[m * 128 + (n - 128)] = f2bf(v);
        }
    }
}

// ---------------- K_score: fused QK^T + psi-gate + exp + num/den reduce ----------------
// 128x128 tile, 4 waves (2x2), each wave 64x64 (acc 4x4). Grid (32,32)=1024 blocks.
// p = exp2(gate[d] * acc) since Q carries 1/sqrt(dk)*log2(e). Ranks pre-scaled by
// 0.25 so d = (int)|dr| directly (d<=1023 guaranteed by input range).
// Partials stored row-major: num_part[row*64 + slot], slot = bn*2 + wn.
// NOTE: no cross-block fences/atomics — R7 showed a per-block device-scope
// __threadfence costs ~100x more than the separate k_out launch.
__global__ __launch_bounds__(256) void k_score(const unsigned short* __restrict__ qb,
                                               const unsigned short* __restrict__ kb,
                                               const float* __restrict__ ranks,
                                               const float* __restrict__ gate,
                                               const float* __restrict__ u,
                                               float* __restrict__ num_part,
                                               float* __restrict__ den_part) {
    __shared__ float g_lds[NUM_EMB];
    __shared__ float rr[128], rc[128], uc[128];
    int tid = threadIdx.x;
    int lane = tid & 63, w = tid >> 6;
    int l15 = lane & 15, lhi = lane >> 4;
    int wm = w >> 1, wn = w & 1;
    int bm = blockIdx.x, bn = blockIdx.y;

    for (int i = tid; i < NUM_EMB; i += 256) g_lds[i] = gate[i];
    if (tid < 128) {
        rr[tid] = ranks[bm * 128 + tid] * 0.25f;
        rc[tid] = ranks[bn * 128 + tid] * 0.25f;
        uc[tid] = u[bn * 128 + tid];
    }
    __syncthreads();

    int row0 = wm * 64;
    int col0 = wn * 64;

    f32x4 zero4 = {0.f, 0.f, 0.f, 0.f};
    f32x4 acc[4][4];
#pragma unroll
    for (int mi = 0; mi < 4; ++mi)
#pragma unroll
        for (int ni = 0; ni < 4; ++ni) acc[mi][ni] = zero4;

#pragma unroll
    for (int k0 = 0; k0 < DKQ; k0 += 32) {
        s16x8 af[4], bf[4];
#pragma unroll
        for (int mi = 0; mi < 4; ++mi)
            af[mi] = ld8(qb + (bm * 128 + row0 + mi * 16 + l15) * DKQ + k0 + lhi * 8);
#pragma unroll
        for (int ni = 0; ni < 4; ++ni)
            bf[ni] = ld8(kb + (bn * 128 + col0 + ni * 16 + l15) * DKQ + k0 + lhi * 8);
#pragma unroll
        for (int mi = 0; mi < 4; ++mi)
#pragma unroll
            for (int ni = 0; ni < 4; ++ni)
                acc[mi][ni] = __builtin_amdgcn_mfma_f32_16x16x32_bf16(af[mi], bf[ni], acc[mi][ni], 0, 0, 0);
    }

    float rreg[4][4];
#pragma unroll
    for (int mi = 0; mi < 4; ++mi)
#pragma unroll
        for (int r = 0; r < 4; ++r) rreg[mi][r] = rr[row0 + mi * 16 + lhi * 4 + r];

    float num[4][4], den[4][4];
#pragma unroll
    for (int mi = 0; mi < 4; ++mi)
#pragma unroll
        for (int r = 0; r < 4; ++r) { num[mi][r] = 0.f; den[mi][r] = 0.f; }

#pragma unroll
    for (int mi = 0; mi < 4; ++mi) {
#pragma unroll
        for (int ni = 0; ni < 4; ++ni) {
            int coll = col0 + ni * 16 + l15;
            float rj = rc[coll];
            float uj = uc[coll];
#pragma unroll
            for (int r = 0; r < 4; ++r) {
                int d = (int)fabsf(rreg[mi][r] - rj);
                float p = exp2f(g_lds[d] * acc[mi][ni][r]);
                den[mi][r] += p;
                num[mi][r] += p * uj;
            }
        }
    }
    int slot = bn * 2 + wn;
#pragma unroll
    for (int mi = 0; mi < 4; ++mi) {
#pragma unroll
        for (int r = 0; r < 4; ++r) {
            float vn = num[mi][r], vd = den[mi][r];
            vn += __shfl_xor(vn, 1); vd += __shfl_xor(vd, 1);
            vn += __shfl_xor(vn, 2); vd += __shfl_xor(vd, 2);
            vn += __shfl_xor(vn, 4); vd += __shfl_xor(vd, 4);
            vn += __shfl_xor(vn, 8); vd += __shfl_xor(vd, 8);
            if (l15 == 0) {
                int row = bm * 128 + row0 + mi * 16 + lhi * 4 + r;
                num_part[row * 64 + slot] = vn;
                den_part[row * 64 + slot] = vd;
            }
        }
    }
}

// ---------------- K_out: out = sigmoid(num/den + wfb), coalesced partials ----------------
__global__ __launch_bounds__(256) void k_out(const float* __restrict__ num_part,
                                             const float* __restrict__ den_part,
                                             const float* __restrict__ wfb,
                                             float* __restrict__ out) {
    int lane = threadIdx.x & 63, w = threadIdx.x >> 6;
    int row = blockIdx.x * 4 + w;
    float vn = num_part[row * 64 + lane];
    float vd = den_part[row * 64 + lane];
#pragma unroll
    for (int m = 1; m < 64; m <<= 1) {
        vn += __shfl_xor(vn, m);
        vd += __shfl_xor(vd, m);
    }
    if (lane == 0) out[row] = 1.f / (1.f + __expf(-(vn / vd + wfb[0])));
}

extern "C" void kernel_launch(void* const* d_in, const int* in_sizes, int n_in,
                              void* d_out, int out_size, void* d_ws, size_t ws_size,
                              hipStream_t stream) {
    const float* X    = (const float*)d_in[0];
    const float* rks  = (const float*)d_in[1];
    const float* Wq_w = (const float*)d_in[2];
    const float* Wq_b = (const float*)d_in[3];
    const float* Wk_w = (const float*)d_in[4];
    const float* Wk_b = (const float*)d_in[5];
    const float* Wv_w = (const float*)d_in[6];
    const float* Wv_b = (const float*)d_in[7];
    const float* remb = (const float*)d_in[8];
    const float* wL_w = (const float*)d_in[9];
    const float* wL_b = (const float*)d_in[10];
    const float* wf_w = (const float*)d_in[11];
    const float* wf_b = (const float*)d_in[12];
    float* out = (float*)d_out;
    char* ws = (char*)d_ws;

    const size_t OFF_GATE  = 0;                     // 1024 f32 (4KB)
    const size_t OFF_WEFF4 = 4096;                  // 2049 f32 (pad 12KB)
    const size_t OFF_QB    = 16384;                 // 4096x128 bf16 (1MB)
    const size_t OFF_KB    = OFF_QB + 1048576;      // 4096x128 bf16 (1MB)
    const size_t OFF_U     = OFF_KB + 1048576;      // 4096 f32 (16KB)
    const size_t OFF_NUM   = OFF_U + 16384;         // 4096x64 f32 (1MB)
    const size_t OFF_DEN   = OFF_NUM + 1048576;     // 4096x64 f32 (1MB)

    float* gate = (float*)(ws + OFF_GATE);
    float* weff4 = (float*)(ws + OFF_WEFF4);
    unsigned short* qb = (unsigned short*)(ws + OFF_QB);
    unsigned short* kb = (unsigned short*)(ws + OFF_KB);
    float* u = (float*)(ws + OFF_U);
    float* num_part = (float*)(ws + OFF_NUM);
    float* den_part = (float*)(ws + OFF_DEN);

    k_prep<<<21, 256, 0, stream>>>(remb, wL_w, wL_b, Wv_w, Wv_b, wf_w, gate, weff4);
    k_proj<<<dim3(256, 2), 256, 0, stream>>>(X, weff4, Wq_w, Wk_w, Wq_b, Wk_b, qb, kb, u);
    k_score<<<dim3(32, 32), 256, 0, stream>>>(qb, kb, rks, gate, u, num_part, den_part);
    k_out<<<1024, 256, 0, stream>>>(num_part, den_part, wf_b, out);
}

// Round 10
// 60.095 us; speedup vs baseline: 1.1044x; 1.1044x over previous
//
#include <hip/hip_runtime.h>
#include <hip/hip_bf16.h>

#define N_ASSETS 4096
#define DMODEL 512
#define DKQ 128
#define NUM_EMB 1024

// Fold 1/sqrt(dk) * log2(e) into stored Q so the score epilogue is exp2(g*acc).
#define SCLQ 0.12752789f

typedef float f32x4 __attribute__((ext_vector_type(4)));
typedef short s16x8 __attribute__((ext_vector_type(8)));

__device__ __forceinline__ unsigned short f2bf(float x) {
    unsigned u = __float_as_uint(x);
    u += 0x7FFF + ((u >> 16) & 1);
    return (unsigned short)(u >> 16);
}

__device__ __forceinline__ unsigned pk2(float lo, float hi) {
    __hip_bfloat162 h = __float22bfloat162_rn(make_float2(lo, hi));
    return *(unsigned*)&h;
}

__device__ __forceinline__ s16x8 ld8(const unsigned short* p) {
    return *(const s16x8*)p;
}

// ---------------- K_prep: fused setup, disjoint block ranges ----------------
// blocks 0..3    : gate[e] = sigmoid(rank_emb[e] @ wL + bL)       (1024)
// blocks 4..131  : Wb[256][512] bf16 = [Wq; Wk], bias[256]
// blocks 132..147: weff4 partials: block r=(s,q) covers dout slice s (128 rows)
//                  x din quarter q (128 cols); coalesced row-major reads.
// block  148     : weff4[2048] = bv . wf
__global__ __launch_bounds__(256) void k_prep(const float* __restrict__ remb,
                                              const float* __restrict__ wLw,
                                              const float* __restrict__ wLb,
                                              const float* __restrict__ Wq,
                                              const float* __restrict__ Wk,
                                              const float* __restrict__ bq,
                                              const float* __restrict__ bk,
                                              const float* __restrict__ Wv,
                                              const float* __restrict__ bv,
                                              const float* __restrict__ wfw,
                                              float* __restrict__ gate,
                                              unsigned short* __restrict__ Wb,
                                              float* __restrict__ bias,
                                              float* __restrict__ weff4) {
    int bid = blockIdx.x;
    int tid = threadIdx.x;
    if (bid < 4) {
        int e = bid * 256 + tid;
        float s = wLb[0];
#pragma unroll
        for (int j = 0; j < 32; ++j) s += remb[e * 32 + j] * wLw[j];
        gate[e] = 1.f / (1.f + __expf(-s));
    } else if (bid < 132) {
        int gid = (bid - 4) * 256 + tid;
        int i4 = gid * 4;
        int row = i4 >> 9;
        int col = i4 & 511;
        const float* src; int r;
        if (row < 128) { src = Wq; r = row; } else { src = Wk; r = row - 128; }
        float4 v = *(const float4*)(src + r * 512 + col);
        ushort4 o;
        o.x = f2bf(v.x); o.y = f2bf(v.y); o.z = f2bf(v.z); o.w = f2bf(v.w);
        *(ushort4*)(Wb + i4) = o;
        if (gid < 256) bias[gid] = (gid < 128) ? bq[gid] : bk[gid - 128];
    } else if (bid < 148) {
        int r = bid - 132;   // 0..15
        int s = r >> 2;      // dout slice (128 rows)
        int q = r & 3;       // din quarter (128 cols)
        if (tid < 128) {
            int din = q * 128 + tid;
            int dbase = s * 128;
            const float* wp = Wv + (size_t)dbase * 512 + din;
            float a = 0.f;
#pragma unroll 8
            for (int j = 0; j < 128; ++j)
                a += wp[(size_t)j * 512] * wfw[dbase + j];
            weff4[s * 512 + din] = a;
        }
    } else {
        if (tid < 64) {
            float s = 0.f;
#pragma unroll
            for (int j = 0; j < 8; ++j) s += bv[tid * 8 + j] * wfw[tid * 8 + j];
#pragma unroll
            for (int m = 1; m < 64; m <<= 1) s += __shfl_xor(s, m);
            if (tid == 0) weff4[2048] = s;
        }
    }
}

// ---------------- K_proj: fused X->regs + u GEMV + Q/K projection ----------------
// Grid (256, 2): block owns 16 rows x 128 cols of [Q|K]. 4 waves, each 32 cols,
// 32 MFMA. 512 blocks = 2 blocks/CU. Wave 0 of y==0 also computes
// u = X . (sum of 4 weff partials) + c.
// NOTE (R9 lesson): keep W staged as bf16 (k_prep) — converting W in-register
// inside the MFMA loop costs 2x load bytes + 8 pk2/MFMA and regressed 6 us.
__global__ __launch_bounds__(256) void k_proj(const float* __restrict__ X,
                                              const float* __restrict__ weff4,
                                              const unsigned short* __restrict__ Wb,
                                              const float* __restrict__ bias,
                                              unsigned short* __restrict__ qb,
                                              unsigned short* __restrict__ kb,
                                              float* __restrict__ u) {
    int tid = threadIdx.x;
    int lane = tid & 63, w = tid >> 6;
    int l15 = lane & 15, lhi = lane >> 4;
    int m0 = blockIdx.x * 16;
    int n0w = blockIdx.y * 128 + w * 32;

    const float* xrow = X + (size_t)(m0 + l15) * DMODEL + lhi * 8;

    s16x8 af[16];
    float us = 0.f;
    bool dou = (w == 0) && (blockIdx.y == 0);
#pragma unroll
    for (int kc = 0; kc < 16; ++kc) {
        float4 a = *(const float4*)(xrow + kc * 32);
        float4 b = *(const float4*)(xrow + kc * 32 + 4);
        if (dou) {
            int off = kc * 32 + lhi * 8;
            float4 p0 = *(const float4*)(weff4 + off);
            float4 p1 = *(const float4*)(weff4 + 512 + off);
            float4 p2 = *(const float4*)(weff4 + 1024 + off);
            float4 p3 = *(const float4*)(weff4 + 1536 + off);
            float4 q0 = *(const float4*)(weff4 + off + 4);
            float4 q1 = *(const float4*)(weff4 + 512 + off + 4);
            float4 q2 = *(const float4*)(weff4 + 1024 + off + 4);
            float4 q3 = *(const float4*)(weff4 + 1536 + off + 4);
            float wax = p0.x + p1.x + p2.x + p3.x;
            float way = p0.y + p1.y + p2.y + p3.y;
            float waz = p0.z + p1.z + p2.z + p3.z;
            float waw = p0.w + p1.w + p2.w + p3.w;
            float wbx = q0.x + q1.x + q2.x + q3.x;
            float wby = q0.y + q1.y + q2.y + q3.y;
            float wbz = q0.z + q1.z + q2.z + q3.z;
            float wbw = q0.w + q1.w + q2.w + q3.w;
            us += a.x * wax + a.y * way + a.z * waz + a.w * waw
                + b.x * wbx + b.y * wby + b.z * wbz + b.w * wbw;
        }
        union { s16x8 v; unsigned q[4]; } fr;
        fr.q[0] = pk2(a.x, a.y);
        fr.q[1] = pk2(a.z, a.w);
        fr.q[2] = pk2(b.x, b.y);
        fr.q[3] = pk2(b.z, b.w);
        af[kc] = fr.v;
    }
    if (dou) {
        us += __shfl_xor(us, 16);
        us += __shfl_xor(us, 32);
        if (lane < 16) u[m0 + lane] = us + weff4[2048];
    }

    f32x4 zero4 = {0.f, 0.f, 0.f, 0.f};
    f32x4 acc[2];
#pragma unroll
    for (int ni = 0; ni < 2; ++ni) acc[ni] = zero4;

#pragma unroll
    for (int k0 = 0; k0 < 16; ++k0) {
#pragma unroll
        for (int ni = 0; ni < 2; ++ni) {
            s16x8 bf = ld8(Wb + (size_t)(n0w + ni * 16 + l15) * 512 + k0 * 32 + lhi * 8);
            acc[ni] = __builtin_amdgcn_mfma_f32_16x16x32_bf16(af[k0], bf, acc[ni], 0, 0, 0);
        }
    }

#pragma unroll
    for (int ni = 0; ni < 2; ++ni) {
        int n = n0w + ni * 16 + l15;
        float bv_ = bias[n];
#pragma unroll
        for (int r = 0; r < 4; ++r) {
            int m = m0 + lhi * 4 + r;
            float v = acc[ni][r] + bv_;
            if (n < 128) qb[m * 128 + n] = f2bf(v * SCLQ);
            else         kb[m * 128 + (n - 128)] = f2bf(v);
        }
    }
}

// ---------------- K_score: fused QK^T + psi-gate + exp + num/den reduce ----------------
// 128x128 tile, 4 waves (2x2), each wave 64x64 (acc 4x4). Grid (32,32)=1024 blocks.
// p = exp2(gate[d] * acc) since Q carries 1/sqrt(dk)*log2(e). Ranks pre-scaled by
// 0.25 so d = (int)|dr| directly (d<=1023 guaranteed by input range).
// Partials stored row-major: num_part[row*64 + slot], slot = bn*2 + wn.
// NOTE: no cross-block fences/atomics — R7 showed a per-block device-scope
// __threadfence costs ~100x more than the separate k_out launch.
__global__ __launch_bounds__(256) void k_score(const unsigned short* __restrict__ qb,
                                               const unsigned short* __restrict__ kb,
                                               const float* __restrict__ ranks,
                                               const float* __restrict__ gate,
                                               const float* __restrict__ u,
                                               float* __restrict__ num_part,
                                               float* __restrict__ den_part) {
    __shared__ float g_lds[NUM_EMB];
    __shared__ float rr[128], rc[128], uc[128];
    int tid = threadIdx.x;
    int lane = tid & 63, w = tid >> 6;
    int l15 = lane & 15, lhi = lane >> 4;
    int wm = w >> 1, wn = w & 1;
    int bm = blockIdx.x, bn = blockIdx.y;

    for (int i = tid; i < NUM_EMB; i += 256) g_lds[i] = gate[i];
    if (tid < 128) {
        rr[tid] = ranks[bm * 128 + tid] * 0.25f;
        rc[tid] = ranks[bn * 128 + tid] * 0.25f;
        uc[tid] = u[bn * 128 + tid];
    }
    __syncthreads();

    int row0 = wm * 64;
    int col0 = wn * 64;

    f32x4 zero4 = {0.f, 0.f, 0.f, 0.f};
    f32x4 acc[4][4];
#pragma unroll
    for (int mi = 0; mi < 4; ++mi)
#pragma unroll
        for (int ni = 0; ni < 4; ++ni) acc[mi][ni] = zero4;

#pragma unroll
    for (int k0 = 0; k0 < DKQ; k0 += 32) {
        s16x8 af[4], bf[4];
#pragma unroll
        for (int mi = 0; mi < 4; ++mi)
            af[mi] = ld8(qb + (bm * 128 + row0 + mi * 16 + l15) * DKQ + k0 + lhi * 8);
#pragma unroll
        for (int ni = 0; ni < 4; ++ni)
            bf[ni] = ld8(kb + (bn * 128 + col0 + ni * 16 + l15) * DKQ + k0 + lhi * 8);
#pragma unroll
        for (int mi = 0; mi < 4; ++mi)
#pragma unroll
            for (int ni = 0; ni < 4; ++ni)
                acc[mi][ni] = __builtin_amdgcn_mfma_f32_16x16x32_bf16(af[mi], bf[ni], acc[mi][ni], 0, 0, 0);
    }

    float rreg[4][4];
#pragma unroll
    for (int mi = 0; mi < 4; ++mi)
#pragma unroll
        for (int r = 0; r < 4; ++r) rreg[mi][r] = rr[row0 + mi * 16 + lhi * 4 + r];

    float num[4][4], den[4][4];
#pragma unroll
    for (int mi = 0; mi < 4; ++mi)
#pragma unroll
        for (int r = 0; r < 4; ++r) { num[mi][r] = 0.f; den[mi][r] = 0.f; }

#pragma unroll
    for (int mi = 0; mi < 4; ++mi) {
#pragma unroll
        for (int ni = 0; ni < 4; ++ni) {
            int coll = col0 + ni * 16 + l15;
            float rj = rc[coll];
            float uj = uc[coll];
#pragma unroll
            for (int r = 0; r < 4; ++r) {
                int d = (int)fabsf(rreg[mi][r] - rj);
                float p = exp2f(g_lds[d] * acc[mi][ni][r]);
                den[mi][r] += p;
                num[mi][r] += p * uj;
            }
        }
    }
    int slot = bn * 2 + wn;
#pragma unroll
    for (int mi = 0; mi < 4; ++mi) {
#pragma unroll
        for (int r = 0; r < 4; ++r) {
            float vn = num[mi][r], vd = den[mi][r];
            vn += __shfl_xor(vn, 1); vd += __shfl_xor(vd, 1);
            vn += __shfl_xor(vn, 2); vd += __shfl_xor(vd, 2);
            vn += __shfl_xor(vn, 4); vd += __shfl_xor(vd, 4);
            vn += __shfl_xor(vn, 8); vd += __shfl_xor(vd, 8);
            if (l15 == 0) {
                int row = bm * 128 + row0 + mi * 16 + lhi * 4 + r;
                num_part[row * 64 + slot] = vn;
                den_part[row * 64 + slot] = vd;
            }
        }
    }
}

// ---------------- K_out: out = sigmoid(num/den + wfb), coalesced partials ----------------
__global__ __launch_bounds__(256) void k_out(const float* __restrict__ num_part,
                                             const float* __restrict__ den_part,
                                             const float* __restrict__ wfb,
                                             float* __restrict__ out) {
    int lane = threadIdx.x & 63, w = threadIdx.x >> 6;
    int row = blockIdx.x * 4 + w;
    float vn = num_part[row * 64 + lane];
    float vd = den_part[row * 64 + lane];
#pragma unroll
    for (int m = 1; m < 64; m <<= 1) {
        vn += __shfl_xor(vn, m);
        vd += __shfl_xor(vd, m);
    }
    if (lane == 0) out[row] = 1.f / (1.f + __expf(-(vn / vd + wfb[0])));
}

extern "C" void kernel_launch(void* const* d_in, const int* in_sizes, int n_in,
                              void* d_out, int out_size, void* d_ws, size_t ws_size,
                              hipStream_t stream) {
    const float* X    = (const float*)d_in[0];
    const float* rks  = (const float*)d_in[1];
    const float* Wq_w = (const float*)d_in[2];
    const float* Wq_b = (const float*)d_in[3];
    const float* Wk_w = (const float*)d_in[4];
    const float* Wk_b = (const float*)d_in[5];
    const float* Wv_w = (const float*)d_in[6];
    const float* Wv_b = (const float*)d_in[7];
    const float* remb = (const float*)d_in[8];
    const float* wL_w = (const float*)d_in[9];
    const float* wL_b = (const float*)d_in[10];
    const float* wf_w = (const float*)d_in[11];
    const float* wf_b = (const float*)d_in[12];
    float* out = (float*)d_out;
    char* ws = (char*)d_ws;

    const size_t OFF_GATE  = 0;                     // 1024 f32 (4KB)
    const size_t OFF_BIAS  = 4096;                  // 256 f32 (pad 4KB)
    const size_t OFF_WEFF4 = 8192;                  // 2049 f32 (pad 12KB)
    const size_t OFF_WB    = 20480;                 // 256x512 bf16 (256KB)
    const size_t OFF_QB    = OFF_WB + 262144;       // 4096x128 bf16 (1MB)
    const size_t OFF_KB    = OFF_QB + 1048576;      // 4096x128 bf16 (1MB)
    const size_t OFF_U     = OFF_KB + 1048576;      // 4096 f32 (16KB)
    const size_t OFF_NUM   = OFF_U + 16384;         // 4096x64 f32 (1MB)
    const size_t OFF_DEN   = OFF_NUM + 1048576;     // 4096x64 f32 (1MB)

    float* gate = (float*)(ws + OFF_GATE);
    float* bias = (float*)(ws + OFF_BIAS);
    float* weff4 = (float*)(ws + OFF_WEFF4);
    unsigned short* Wb = (unsigned short*)(ws + OFF_WB);
    unsigned short* qb = (unsigned short*)(ws + OFF_QB);
    unsigned short* kb = (unsigned short*)(ws + OFF_KB);
    float* u = (float*)(ws + OFF_U);
    float* num_part = (float*)(ws + OFF_NUM);
    float* den_part = (float*)(ws + OFF_DEN);

    k_prep<<<149, 256, 0, stream>>>(remb, wL_w, wL_b, Wq_w, Wk_w, Wq_b, Wk_b,
                                    Wv_w, Wv_b, wf_w, gate, Wb, bias, weff4);
    k_proj<<<dim3(256, 2), 256, 0, stream>>>(X, weff4, Wb, bias, qb, kb, u);
    k_score<<<dim3(32, 32), 256, 0, stream>>>(qb, kb, rks, gate, u, num_part, den_part);
    k_out<<<1024, 256, 0, stream>>>(num_part, den_part, wf_b, out);
}